// Round 9
// baseline (313.752 us; speedup 1.0000x reference)
//
#include <hip/hip_runtime.h>

#define Tn   2048
#define Dn   1024
#define KDn  256
#define NHn  16
#define NKVn 4
#define Rn   4096   // B*T

typedef short bf16x8 __attribute__((ext_vector_type(8)));
typedef float f32x4  __attribute__((ext_vector_type(4)));

// ---- device-global intermediates; referenced ONLY from device code ---------
__device__ unsigned short g_q[(size_t)Rn * Dn];              // 8 MB [b][t][h][d]
__device__ unsigned short g_k[(size_t)Rn * KDn];             // 2 MB [b][t][kvh][d]
__device__ unsigned short g_vt[(size_t)2 * NKVn * 64 * Tn];  // 2 MB [b][kvh][d][t]
__device__ unsigned short g_y[(size_t)Rn * Dn];              // 8 MB [b][t][h][d]
__device__ unsigned short g_xb[(size_t)Rn * Dn];             // 8 MB bf16 x
__device__ unsigned short g_wq[(size_t)Dn * Dn];             // 2 MB
__device__ unsigned short g_wk[(size_t)KDn * Dn];            // 0.5 MB
__device__ unsigned short g_wv[(size_t)KDn * Dn];            // 0.5 MB
__device__ unsigned short g_wp[(size_t)Dn * Dn];             // 2 MB
__device__ float g_tq[Rn * 8];
__device__ float g_tv[Rn * 8];

static __device__ __forceinline__ float bf2f(unsigned short u) {
    return __uint_as_float(((unsigned)u) << 16);
}
static __device__ __forceinline__ unsigned short f2bf(float f) {
    unsigned u = __float_as_uint(f);
    u += 0x7fffu + ((u >> 16) & 1u);   // round-to-nearest-even
    return (unsigned short)(u >> 16);
}
static __device__ __forceinline__ unsigned pk2bf(float a, float b) {
    return (unsigned)f2bf(a) | ((unsigned)f2bf(b) << 16);
}
static __device__ __forceinline__ float wave_sum(float s) {
    #pragma unroll
    for (int off = 32; off; off >>= 1) s += __shfl_xor(s, off);
    return s;
}

// ---------------- fp32 -> bf16 pre-cast (SEL: 0=x,1=Wq,2=Wk,3=Wv,4=Wp) ------
template<int SEL>
__global__ __launch_bounds__(256)
void cast_bf16(const float* __restrict__ src, int n4) {
    unsigned short* dst = (SEL == 0) ? g_xb : (SEL == 1) ? g_wq :
                          (SEL == 2) ? g_wk : (SEL == 3) ? g_wv : g_wp;
    int i = blockIdx.x * 256 + threadIdx.x;
    if (i < n4) {
        float4 v = ((const float4*)src)[i];
        ((uint2*)dst)[i] = make_uint2(pk2bf(v.x, v.y), pk2bf(v.z, v.w));
    }
}

// ---------------- LoRA temporaries: tq = x@Aq^T, tv = x@Av^T ----------------
__global__ __launch_bounds__(256)
void lora_tmp(const float* __restrict__ x,
              const float* __restrict__ Aq,
              const float* __restrict__ Av) {
    int tid = threadIdx.x, wave = tid >> 6, lane = tid & 63;
    int row = blockIdx.x * 4 + wave;
    const float* xr = x + (size_t)row * Dn;
    float aq[8], av[8];
    #pragma unroll
    for (int r = 0; r < 8; r++) { aq[r] = 0.f; av[r] = 0.f; }
    for (int it = 0; it < Dn / 64; it++) {
        int j = lane + it * 64;
        float xv = xr[j];
        #pragma unroll
        for (int r = 0; r < 8; r++) aq[r] += xv * Aq[r * Dn + j];
        #pragma unroll
        for (int r = 0; r < 8; r++) av[r] += xv * Av[r * Dn + j];
    }
    #pragma unroll
    for (int r = 0; r < 8; r++) { aq[r] = wave_sum(aq[r]); av[r] = wave_sum(av[r]); }
    if (lane == 0) {
        #pragma unroll
        for (int r = 0; r < 8; r++) { g_tq[row * 8 + r] = aq[r]; g_tv[row * 8 + r] = av[r]; }
    }
}

// ---- MFMA GEMM, 128x64 tile, bf16 in: C = A @ W^T (+ t @ Bl^T) -------------
// DST picks W and C: 0: W=g_wq C=g_q | 1: g_wk,g_k | 2: g_wv,g_vt(transposed)
//                    3: W=g_wp C=Cout(fp32).  ASEL: 0=g_xb, 1=g_y.
// Wave w computes rows m0+w*32..+31 x all 64 cols (2x4 frags, 8 MFMA/kstep).
template<int LORA, int DST, int ASEL, int TSEL>
__global__ __launch_bounds__(256, 2)
void gemm_bt(float* __restrict__ Cout, const float* __restrict__ Bl,
             int M, int N, int K) {
    const unsigned short* A = (ASEL == 0) ? g_xb : g_y;
    const unsigned short* W = (DST == 0) ? g_wq : (DST == 1) ? g_wk :
                              (DST == 2) ? g_wv : g_wp;
    const float* tl = (TSEL == 0) ? g_tq : g_tv;

    __shared__ __align__(16) unsigned short As[128 * 40];
    __shared__ __align__(16) unsigned short Ws[64 * 40];
    int tid = threadIdx.x;
    int w = tid >> 6, lane = tid & 63;
    int m_ = lane & 15, quad = lane >> 4;
    int n0 = blockIdx.x * 64, m0 = blockIdx.y * 128;
    int arow = tid >> 1, aseg = (tid & 1) * 16;   // A: 128 rows x 2 x 16 elems
    int wrow = tid >> 2, wseg = (tid & 3) * 8;    // W: 64 rows x 4 x 8 elems

    f32x4 acc[2][4];
    #pragma unroll
    for (int im = 0; im < 2; im++)
        #pragma unroll
        for (int in = 0; in < 4; in++) acc[im][in] = (f32x4){0.f, 0.f, 0.f, 0.f};

    for (int k0 = 0; k0 < K; k0 += 32) {
        __syncthreads();
        uint4 a0 = *(const uint4*)(A + (size_t)(m0 + arow) * K + k0 + aseg);
        uint4 a1 = *(const uint4*)(A + (size_t)(m0 + arow) * K + k0 + aseg + 8);
        uint4 wv = *(const uint4*)(W + (size_t)(n0 + wrow) * K + k0 + wseg);
        *(uint4*)&As[arow * 40 + aseg] = a0;
        *(uint4*)&As[arow * 40 + aseg + 8] = a1;
        *(uint4*)&Ws[wrow * 40 + wseg] = wv;
        __syncthreads();
        bf16x8 bf[4];
        #pragma unroll
        for (int in = 0; in < 4; in++)
            bf[in] = *(const bf16x8*)&Ws[(in * 16 + m_) * 40 + quad * 8];
        #pragma unroll
        for (int im = 0; im < 2; im++) {
            bf16x8 af = *(const bf16x8*)&As[(w * 32 + im * 16 + m_) * 40 + quad * 8];
            #pragma unroll
            for (int in = 0; in < 4; in++)
                acc[im][in] = __builtin_amdgcn_mfma_f32_16x16x32_bf16(af, bf[in], acc[im][in], 0, 0, 0);
        }
    }

    float blc[4][8];
    if (LORA) {
        #pragma unroll
        for (int in = 0; in < 4; in++) {
            const float* bp = Bl + (size_t)(n0 + in * 16 + m_) * 8;
            #pragma unroll
            for (int j = 0; j < 8; j++) blc[in][j] = bp[j];
        }
    }
    #pragma unroll
    for (int im = 0; im < 2; im++) {
        #pragma unroll
        for (int r = 0; r < 4; r++) {
            int row = m0 + w * 32 + im * 16 + quad * 4 + r;
            float tv8[8];
            if (LORA) {
                const float* tp = tl + (size_t)row * 8;
                #pragma unroll
                for (int j = 0; j < 8; j++) tv8[j] = tp[j];
            }
            #pragma unroll
            for (int in = 0; in < 4; in++) {
                int col = n0 + in * 16 + m_;
                float val = acc[im][in][r];
                if (LORA) {
                    #pragma unroll
                    for (int j = 0; j < 8; j++) val += tv8[j] * blc[in][j];
                }
                if (DST == 3) {
                    Cout[(size_t)row * N + col] = val;
                } else if (DST == 2) {
                    // transposed V store: [b][kvh][d][t]
                    int b = row >> 11, t = row & (Tn - 1);
                    int kvh = col >> 6, d = col & 63;
                    g_vt[(((size_t)(b * NKVn + kvh) * 64) + d) * Tn + t] = f2bf(val);
                } else {
                    unsigned short* C = (DST == 0) ? g_q : g_k;
                    C[(size_t)row * N + col] = f2bf(val);
                }
            }
        }
    }
}

// -------- RMSNorm + partial RoPE (+gain for q), in place on g_q / g_k -------
__global__ __launch_bounds__(256)
void nrg_kernel(const float* __restrict__ gain) {
    int tid = threadIdx.x;
    int u = blockIdx.y * 4 + (tid >> 6);   // 0..15: q heads, 16..19: k heads
    int lane = tid & 63;
    int row = blockIdx.x;
    int t = row & (Tn - 1);

    unsigned short* buf;
    size_t off;
    if (u < 16) { buf = g_q; off = (size_t)row * Dn + u * 64 + lane; }
    else        { buf = g_k; off = (size_t)row * KDn + (u - 16) * 64 + lane; }

    float v = bf2f(buf[off]);
    float s = wave_sum(v * v);
    float xv = v * rsqrtf(s * (1.0f / 64.0f) + 1.1920929e-7f);
    float p = __shfl_xor(xv, 8);
    if (lane < 16) {
        int j = lane & 7;
        float fr = (float)t * exp2f(-(float)j * 1.6609640474436813f); // base^(-j/8)
        float c = cosf(fr), sn = sinf(fr);
        xv = (lane < 8) ? (xv * c + p * sn) : (p * sn - xv * c);
    }
    if (u < 16) xv *= gain[u];
    buf[off] = f2bf(xv);
}

// -------- MFMA flash attention, block = 4 heads sharing one kv group --------
// (unchanged from r8 except: longest blocks launch first to trim the tail)
__global__ __launch_bounds__(256, 4)
void attn_kernel() {
    __shared__ __align__(16) unsigned short KS[2][32 * 72];  // row=key, 144B stride
    __shared__ __align__(16) unsigned short VS[2][64 * 40];  // row=d,   80B stride
    __shared__ __align__(16) unsigned short Pt[4][16 * 40];  // per-wave P^T
    const float qsc = 0.125f * 1.44269504088896f;  // 1/sqrt(64) * log2(e)
    int tid = threadIdx.x;
    int w = tid >> 6, lane = tid & 63;
    int q_ = lane & 15, quad = lane >> 4;
    int b = blockIdx.z, kvh = blockIdx.y, h = kvh * 4 + w;
    int qb = (gridDim.x - 1 - blockIdx.x) * 16;   // longest first
    int qg = qb + q_;

    const unsigned short* qrow =
        g_q + ((size_t)(b * Tn + qg) * NHn + h) * 64 + quad * 8;
    bf16x8 Qf0 = *(const bf16x8*)qrow;
    bf16x8 Qf1 = *(const bf16x8*)(qrow + 32);

    int krow = tid >> 3, kseg = tid & 7;   // K: 32 rows x 8 x 16B
    int vrow = tid >> 2, vseg = tid & 3;   // V^T: 64 rows x 4 x 16B
    const unsigned short* kgp =
        g_k + ((size_t)(b * Tn + krow) * NKVn + kvh) * 64 + kseg * 8;
    const unsigned short* vgp =
        g_vt + ((size_t)(b * NKVn + kvh) * 64 + vrow) * Tn + vseg * 8;

    f32x4 accO[4];
    #pragma unroll
    for (int i = 0; i < 4; i++) accO[i] = (f32x4){0.f, 0.f, 0.f, 0.f};
    float lsum = 0.f;
    int ntiles = (qb + 47) >> 5;   // ceil((qb+16)/32); block-uniform

    {
        uint4 kr = *(const uint4*)kgp;
        uint4 vr = *(const uint4*)vgp;
        *(uint4*)&KS[0][krow * 72 + kseg * 8] = kr;
        *(uint4*)&VS[0][vrow * 40 + vseg * 8] = vr;
    }
    __syncthreads();

    for (int kt = 0; kt < ntiles; kt++) {
        int cur = kt & 1, nxt = cur ^ 1;
        uint4 krn = make_uint4(0, 0, 0, 0), vrn = make_uint4(0, 0, 0, 0);
        if (kt + 1 < ntiles) {
            krn = *(const uint4*)(kgp + (size_t)(kt + 1) * (32 * NKVn * 64));
            vrn = *(const uint4*)(vgp + (kt + 1) * 32);
        }

        const unsigned short* ks = &KS[cur][0];
        const unsigned short* vs = &VS[cur][0];
        bf16x8 k00 = *(const bf16x8*)&ks[q_ * 72 + quad * 8];
        bf16x8 k01 = *(const bf16x8*)&ks[q_ * 72 + 32 + quad * 8];
        bf16x8 k10 = *(const bf16x8*)&ks[(16 + q_) * 72 + quad * 8];
        bf16x8 k11 = *(const bf16x8*)&ks[(16 + q_) * 72 + 32 + quad * 8];
        f32x4 s0 = (f32x4){0.f, 0.f, 0.f, 0.f};
        f32x4 s1 = (f32x4){0.f, 0.f, 0.f, 0.f};
        s0 = __builtin_amdgcn_mfma_f32_16x16x32_bf16(k00, Qf0, s0, 0, 0, 0);
        s0 = __builtin_amdgcn_mfma_f32_16x16x32_bf16(k01, Qf1, s0, 0, 0, 0);
        s1 = __builtin_amdgcn_mfma_f32_16x16x32_bf16(k10, Qf0, s1, 0, 0, 0);
        s1 = __builtin_amdgcn_mfma_f32_16x16x32_bf16(k11, Qf1, s1, 0, 0, 0);

        if (kt == ntiles - 1) {
            int k0 = kt * 32 + quad * 4;
            #pragma unroll
            for (int r = 0; r < 4; r++) {
                if (k0 + r > qg)      s0[r] = -1e30f;
                if (k0 + 16 + r > qg) s1[r] = -1e30f;
            }
        }
        float p0[4], p1[4];
        #pragma unroll
        for (int r = 0; r < 4; r++) { p0[r] = exp2f(s0[r] * qsc); lsum += p0[r]; }
        #pragma unroll
        for (int r = 0; r < 4; r++) { p1[r] = exp2f(s1[r] * qsc); lsum += p1[r]; }

        unsigned short* pb = &Pt[w][0];
        *(uint2*)&pb[q_ * 40 + quad * 4] =
            make_uint2(pk2bf(p0[0], p0[1]), pk2bf(p0[2], p0[3]));
        *(uint2*)&pb[q_ * 40 + 16 + quad * 4] =
            make_uint2(pk2bf(p1[0], p1[1]), pk2bf(p1[2], p1[3]));
        bf16x8 pf = *(const bf16x8*)&pb[q_ * 40 + quad * 8];

        #pragma unroll
        for (int c = 0; c < 4; c++) {
            bf16x8 vf = *(const bf16x8*)&vs[(c * 16 + q_) * 40 + quad * 8];
            accO[c] = __builtin_amdgcn_mfma_f32_16x16x32_bf16(vf, pf, accO[c], 0, 0, 0);
        }

        if (kt + 1 < ntiles) {
            *(uint4*)&KS[nxt][krow * 72 + kseg * 8] = krn;
            *(uint4*)&VS[nxt][vrow * 40 + vseg * 8] = vrn;
        }
        __syncthreads();
    }

    lsum += __shfl_xor(lsum, 16);
    lsum += __shfl_xor(lsum, 32);
    float invl = 1.0f / lsum;
    unsigned short* yp = g_y + ((size_t)(b * Tn + qg) * NHn + h) * 64;
    #pragma unroll
    for (int c = 0; c < 4; c++) {
        uint2 o = make_uint2(pk2bf(accO[c][0] * invl, accO[c][1] * invl),
                             pk2bf(accO[c][2] * invl, accO[c][3] * invl));
        *(uint2*)&yp[c * 16 + quad * 4] = o;
    }
}

// ----------------------------------------------------------------------------
extern "C" void kernel_launch(void* const* d_in, const int* in_sizes, int n_in,
                              void* d_out, int out_size, void* d_ws, size_t ws_size,
                              hipStream_t stream) {
    const float* x  = (const float*)d_in[0];
    const float* Wq = (const float*)d_in[1];
    const float* Wk = (const float*)d_in[2];
    const float* Wv = (const float*)d_in[3];
    const float* Wp = (const float*)d_in[4];
    const float* qg = (const float*)d_in[5];
    const float* Aq = (const float*)d_in[6];
    const float* Bq = (const float*)d_in[7];
    const float* Av = (const float*)d_in[8];
    const float* Bv = (const float*)d_in[9];
    float* out = (float*)d_out;

    lora_tmp<<<dim3(Rn / 4), dim3(256), 0, stream>>>(x, Aq, Av);
    cast_bf16<0><<<dim3((Rn * Dn / 4 + 255) / 256), dim3(256), 0, stream>>>(x, Rn * Dn / 4);
    cast_bf16<1><<<dim3((Dn * Dn / 4 + 255) / 256), dim3(256), 0, stream>>>(Wq, Dn * Dn / 4);
    cast_bf16<2><<<dim3((KDn * Dn / 4 + 255) / 256), dim3(256), 0, stream>>>(Wk, KDn * Dn / 4);
    cast_bf16<3><<<dim3((KDn * Dn / 4 + 255) / 256), dim3(256), 0, stream>>>(Wv, KDn * Dn / 4);
    cast_bf16<4><<<dim3((Dn * Dn / 4 + 255) / 256), dim3(256), 0, stream>>>(Wp, Dn * Dn / 4);

    gemm_bt<1, 0, 0, 0><<<dim3(Dn / 64, Rn / 128), dim3(256), 0, stream>>>(
        nullptr, Bq, Rn, Dn, Dn);
    gemm_bt<0, 1, 0, 0><<<dim3(KDn / 64, Rn / 128), dim3(256), 0, stream>>>(
        nullptr, nullptr, Rn, KDn, Dn);
    gemm_bt<1, 2, 0, 1><<<dim3(KDn / 64, Rn / 128), dim3(256), 0, stream>>>(
        nullptr, Bv, Rn, KDn, Dn);
    nrg_kernel<<<dim3(Rn, 5), dim3(256), 0, stream>>>(qg);
    attn_kernel<<<dim3(Tn / 16, NKVn, 2), dim3(256), 0, stream>>>();
    gemm_bt<0, 3, 1, 0><<<dim3(Dn / 64, Rn / 128), dim3(256), 0, stream>>>(
        out, nullptr, Rn, Dn, Dn);
}

// Round 10
// 298.440 us; speedup vs baseline: 1.0513x; 1.0513x over previous
//
#include <hip/hip_runtime.h>

#define Tn   2048
#define Dn   1024
#define KDn  256
#define NHn  16
#define NKVn 4
#define Rn   4096   // B*T

typedef short bf16x8 __attribute__((ext_vector_type(8)));
typedef float f32x4  __attribute__((ext_vector_type(4)));
typedef const __attribute__((address_space(1))) unsigned* gas_p;
typedef __attribute__((address_space(3))) unsigned* las_p;

// ---- device-global intermediates; referenced ONLY from device code ---------
__device__ unsigned short g_q[(size_t)Rn * Dn];              // 8 MB [b][t][h][d]
__device__ unsigned short g_k[(size_t)Rn * KDn];             // 2 MB [b][t][kvh][d]
__device__ unsigned short g_vt[(size_t)2 * NKVn * 64 * Tn];  // 2 MB [b][kvh][d][t]
__device__ unsigned short g_y[(size_t)Rn * Dn];              // 8 MB [b][t][h][d]
__device__ unsigned short g_xb[(size_t)Rn * Dn];             // 8 MB bf16 x
__device__ unsigned short g_wq[(size_t)Dn * Dn];
__device__ unsigned short g_wk[(size_t)KDn * Dn];
__device__ unsigned short g_wv[(size_t)KDn * Dn];
__device__ unsigned short g_wp[(size_t)Dn * Dn];
__device__ float g_tq[Rn * 8];
__device__ float g_tv[Rn * 8];

static __device__ __forceinline__ float bf2f(unsigned short u) {
    return __uint_as_float(((unsigned)u) << 16);
}
static __device__ __forceinline__ unsigned short f2bf(float f) {
    unsigned u = __float_as_uint(f);
    u += 0x7fffu + ((u >> 16) & 1u);   // round-to-nearest-even
    return (unsigned short)(u >> 16);
}
static __device__ __forceinline__ unsigned pk2bf(float a, float b) {
    return (unsigned)f2bf(a) | ((unsigned)f2bf(b) << 16);
}
static __device__ __forceinline__ float wave_sum(float s) {
    #pragma unroll
    for (int off = 32; off; off >>= 1) s += __shfl_xor(s, off);
    return s;
}

// ------- LoRA temporaries tq/tv = x@A^T  +  fused x fp32->bf16 cast ---------
__global__ __launch_bounds__(256)
void lora_tmp(const float* __restrict__ x,
              const float* __restrict__ Aq,
              const float* __restrict__ Av) {
    int tid = threadIdx.x, wave = tid >> 6, lane = tid & 63;
    int row = blockIdx.x * 4 + wave;
    const float2* xr = (const float2*)(x + (size_t)row * Dn);
    unsigned* xbo = (unsigned*)g_xb + (size_t)row * (Dn / 2);
    float aq[8], av[8];
    #pragma unroll
    for (int r = 0; r < 8; r++) { aq[r] = 0.f; av[r] = 0.f; }
    for (int it = 0; it < Dn / 128; it++) {
        int j = it * 64 + lane;
        float2 xv = xr[j];
        xbo[j] = pk2bf(xv.x, xv.y);
        #pragma unroll
        for (int r = 0; r < 8; r++) {
            float2 a2 = ((const float2*)(Aq + (size_t)r * Dn))[j];
            aq[r] += xv.x * a2.x + xv.y * a2.y;
        }
        #pragma unroll
        for (int r = 0; r < 8; r++) {
            float2 a2 = ((const float2*)(Av + (size_t)r * Dn))[j];
            av[r] += xv.x * a2.x + xv.y * a2.y;
        }
    }
    #pragma unroll
    for (int r = 0; r < 8; r++) { aq[r] = wave_sum(aq[r]); av[r] = wave_sum(av[r]); }
    if (lane == 0) {
        #pragma unroll
        for (int r = 0; r < 8; r++) { g_tq[row * 8 + r] = aq[r]; g_tv[row * 8 + r] = av[r]; }
    }
}

// ---------------- single fused weight cast (Wq|Wk|Wv|Wp -> bf16) ------------
#define NQ4 (Dn * Dn / 4)
#define NK4 (KDn * Dn / 4)
__global__ __launch_bounds__(256)
void cast_w(const float* __restrict__ Wq, const float* __restrict__ Wk,
            const float* __restrict__ Wv, const float* __restrict__ Wp) {
    int i = blockIdx.x * 256 + threadIdx.x;
    const float* src; unsigned short* dst; int o;
    if      (i < NQ4)                 { src = Wq; dst = g_wq; o = i; }
    else if (i < NQ4 + NK4)           { src = Wk; dst = g_wk; o = i - NQ4; }
    else if (i < NQ4 + 2 * NK4)       { src = Wv; dst = g_wv; o = i - NQ4 - NK4; }
    else                              { src = Wp; dst = g_wp; o = i - NQ4 - 2 * NK4; }
    float4 v = ((const float4*)src)[o];
    ((uint2*)dst)[o] = make_uint2(pk2bf(v.x, v.y), pk2bf(v.z, v.w));
}

// ---- MFMA GEMM, 128x64 tile, m97-style global_load_lds + LDS double-buffer -
// DST: 0: W=g_wq C=g_q | 1: g_wk,g_k | 2: g_wv,g_vt(transposed) | 3: g_wp,
// C=Cout fp32.  ASEL: 0=g_xb, 1=g_y.  TSEL: 0=g_tq, 1=g_tv.
// K-loop: sync -> gll prefetch(next buf) -> ds_read+MFMA(cur buf).
template<int LORA, int DST, int ASEL, int TSEL>
__global__ __launch_bounds__(256, 2)
void gemm_bt(float* __restrict__ Cout, const float* __restrict__ Bl,
             int M, int N, int K) {
    const unsigned short* A = (ASEL == 0) ? g_xb : g_y;
    const unsigned short* W = (DST == 0) ? g_wq : (DST == 1) ? g_wk :
                              (DST == 2) ? g_wv : g_wp;
    const float* tl = (TSEL == 0) ? g_tq : g_tv;

    __shared__ __align__(16) unsigned short As[2][128 * 32];  // 64B rows, no pad
    __shared__ __align__(16) unsigned short Ws[2][64 * 32];
    int tid = threadIdx.x;
    int w = tid >> 6, lane = tid & 63;
    int m_ = lane & 15, quad = lane >> 4;
    int n0 = blockIdx.x * 64, m0 = blockIdx.y * 128;

    // gll lane mapping: lane -> (row = base + lane/4, 16B seg = lane&3)
    int lrow = lane >> 2, lseg = (lane & 3) * 8;
    const unsigned short* agp0 = A + (size_t)(m0 + w * 32 + lrow) * K + lseg;
    const unsigned short* agp1 = A + (size_t)(m0 + w * 32 + 16 + lrow) * K + lseg;
    const unsigned short* wgp  = W + (size_t)(n0 + w * 16 + lrow) * K + lseg;
    int albase0 = (w * 32) * 32;        // shorts
    int albase1 = (w * 32 + 16) * 32;
    int wlbase  = (w * 16) * 32;

    f32x4 acc[2][4];
    #pragma unroll
    for (int im = 0; im < 2; im++)
        #pragma unroll
        for (int in = 0; in < 4; in++) acc[im][in] = (f32x4){0.f, 0.f, 0.f, 0.f};

    // prologue: stage k0=0 into buffer 0
    __builtin_amdgcn_global_load_lds((gas_p)agp0, (las_p)&As[0][albase0], 16, 0, 0);
    __builtin_amdgcn_global_load_lds((gas_p)agp1, (las_p)&As[0][albase1], 16, 0, 0);
    __builtin_amdgcn_global_load_lds((gas_p)wgp,  (las_p)&Ws[0][wlbase],  16, 0, 0);

    int nk = K / 32;
    for (int kt = 0; kt < nk; kt++) {
        __syncthreads();                      // drains gll writes of this buf
        int cur = kt & 1, nxt = cur ^ 1;
        if (kt + 1 < nk) {                    // prefetch flies under MFMAs
            int ko = (kt + 1) * 32;
            __builtin_amdgcn_global_load_lds((gas_p)(agp0 + ko), (las_p)&As[nxt][albase0], 16, 0, 0);
            __builtin_amdgcn_global_load_lds((gas_p)(agp1 + ko), (las_p)&As[nxt][albase1], 16, 0, 0);
            __builtin_amdgcn_global_load_lds((gas_p)(wgp  + ko), (las_p)&Ws[nxt][wlbase],  16, 0, 0);
        }
        bf16x8 bf[4];
        #pragma unroll
        for (int in = 0; in < 4; in++)
            bf[in] = *(const bf16x8*)&Ws[cur][(in * 16 + m_) * 32 + quad * 8];
        #pragma unroll
        for (int im = 0; im < 2; im++) {
            bf16x8 af = *(const bf16x8*)&As[cur][(w * 32 + im * 16 + m_) * 32 + quad * 8];
            #pragma unroll
            for (int in = 0; in < 4; in++)
                acc[im][in] = __builtin_amdgcn_mfma_f32_16x16x32_bf16(af, bf[in], acc[im][in], 0, 0, 0);
        }
    }

    float blc[4][8];
    if (LORA) {
        #pragma unroll
        for (int in = 0; in < 4; in++) {
            const float* bp = Bl + (size_t)(n0 + in * 16 + m_) * 8;
            #pragma unroll
            for (int j = 0; j < 8; j++) blc[in][j] = bp[j];
        }
    }
    #pragma unroll
    for (int im = 0; im < 2; im++) {
        #pragma unroll
        for (int r = 0; r < 4; r++) {
            int row = m0 + w * 32 + im * 16 + quad * 4 + r;
            float tv8[8];
            if (LORA) {
                const float* tp = tl + (size_t)row * 8;
                #pragma unroll
                for (int j = 0; j < 8; j++) tv8[j] = tp[j];
            }
            #pragma unroll
            for (int in = 0; in < 4; in++) {
                int col = n0 + in * 16 + m_;
                float val = acc[im][in][r];
                if (LORA) {
                    #pragma unroll
                    for (int j = 0; j < 8; j++) val += tv8[j] * blc[in][j];
                }
                if (DST == 3) {
                    Cout[(size_t)row * N + col] = val;
                } else if (DST == 2) {
                    int b = row >> 11, t = row & (Tn - 1);
                    int kvh = col >> 6, d = col & 63;
                    g_vt[(((size_t)(b * NKVn + kvh) * 64) + d) * Tn + t] = f2bf(val);
                } else {
                    unsigned short* C = (DST == 0) ? g_q : g_k;
                    C[(size_t)row * N + col] = f2bf(val);
                }
            }
        }
    }
}

// -------- RMSNorm + partial RoPE (+gain for q), in place on g_q / g_k -------
__global__ __launch_bounds__(256)
void nrg_kernel(const float* __restrict__ gain) {
    int tid = threadIdx.x;
    int u = blockIdx.y * 4 + (tid >> 6);   // 0..15: q heads, 16..19: k heads
    int lane = tid & 63;
    int row = blockIdx.x;
    int t = row & (Tn - 1);

    unsigned short* buf;
    size_t off;
    if (u < 16) { buf = g_q; off = (size_t)row * Dn + u * 64 + lane; }
    else        { buf = g_k; off = (size_t)row * KDn + (u - 16) * 64 + lane; }

    float v = bf2f(buf[off]);
    float s = wave_sum(v * v);
    float xv = v * rsqrtf(s * (1.0f / 64.0f) + 1.1920929e-7f);
    float p = __shfl_xor(xv, 8);
    if (lane < 16) {
        int j = lane & 7;
        float fr = (float)t * exp2f(-(float)j * 1.6609640474436813f); // base^(-j/8)
        float c = cosf(fr), sn = sinf(fr);
        xv = (lane < 8) ? (xv * c + p * sn) : (p * sn - xv * c);
    }
    if (u < 16) xv *= gain[u];
    buf[off] = f2bf(xv);
}

// -------- MFMA flash attention, block = 4 heads sharing one kv group --------
// (r8-exact: LDS K/V double-buffer, static softmax, natural block order)
__global__ __launch_bounds__(256, 4)
void attn_kernel() {
    __shared__ __align__(16) unsigned short KS[2][32 * 72];
    __shared__ __align__(16) unsigned short VS[2][64 * 40];
    __shared__ __align__(16) unsigned short Pt[4][16 * 40];
    const float qsc = 0.125f * 1.44269504088896f;  // 1/sqrt(64) * log2(e)
    int tid = threadIdx.x;
    int w = tid >> 6, lane = tid & 63;
    int q_ = lane & 15, quad = lane >> 4;
    int b = blockIdx.z, kvh = blockIdx.y, h = kvh * 4 + w;
    int qb = blockIdx.x * 16;
    int qg = qb + q_;

    const unsigned short* qrow =
        g_q + ((size_t)(b * Tn + qg) * NHn + h) * 64 + quad * 8;
    bf16x8 Qf0 = *(const bf16x8*)qrow;
    bf16x8 Qf1 = *(const bf16x8*)(qrow + 32);

    int krow = tid >> 3, kseg = tid & 7;
    int vrow = tid >> 2, vseg = tid & 3;
    const unsigned short* kgp =
        g_k + ((size_t)(b * Tn + krow) * NKVn + kvh) * 64 + kseg * 8;
    const unsigned short* vgp =
        g_vt + ((size_t)(b * NKVn + kvh) * 64 + vrow) * Tn + vseg * 8;

    f32x4 accO[4];
    #pragma unroll
    for (int i = 0; i < 4; i++) accO[i] = (f32x4){0.f, 0.f, 0.f, 0.f};
    float lsum = 0.f;
    int ntiles = (qb + 47) >> 5;

    {
        uint4 kr = *(const uint4*)kgp;
        uint4 vr = *(const uint4*)vgp;
        *(uint4*)&KS[0][krow * 72 + kseg * 8] = kr;
        *(uint4*)&VS[0][vrow * 40 + vseg * 8] = vr;
    }
    __syncthreads();

    for (int kt = 0; kt < ntiles; kt++) {
        int cur = kt & 1, nxt = cur ^ 1;
        uint4 krn = make_uint4(0, 0, 0, 0), vrn = make_uint4(0, 0, 0, 0);
        if (kt + 1 < ntiles) {
            krn = *(const uint4*)(kgp + (size_t)(kt + 1) * (32 * NKVn * 64));
            vrn = *(const uint4*)(vgp + (kt + 1) * 32);
        }

        const unsigned short* ks = &KS[cur][0];
        const unsigned short* vs = &VS[cur][0];
        bf16x8 k00 = *(const bf16x8*)&ks[q_ * 72 + quad * 8];
        bf16x8 k01 = *(const bf16x8*)&ks[q_ * 72 + 32 + quad * 8];
        bf16x8 k10 = *(const bf16x8*)&ks[(16 + q_) * 72 + quad * 8];
        bf16x8 k11 = *(const bf16x8*)&ks[(16 + q_) * 72 + 32 + quad * 8];
        f32x4 s0 = (f32x4){0.f, 0.f, 0.f, 0.f};
        f32x4 s1 = (f32x4){0.f, 0.f, 0.f, 0.f};
        s0 = __builtin_amdgcn_mfma_f32_16x16x32_bf16(k00, Qf0, s0, 0, 0, 0);
        s0 = __builtin_amdgcn_mfma_f32_16x16x32_bf16(k01, Qf1, s0, 0, 0, 0);
        s1 = __builtin_amdgcn_mfma_f32_16x16x32_bf16(k10, Qf0, s1, 0, 0, 0);
        s1 = __builtin_amdgcn_mfma_f32_16x16x32_bf16(k11, Qf1, s1, 0, 0, 0);

        if (kt == ntiles - 1) {
            int k0 = kt * 32 + quad * 4;
            #pragma unroll
            for (int r = 0; r < 4; r++) {
                if (k0 + r > qg)      s0[r] = -1e30f;
                if (k0 + 16 + r > qg) s1[r] = -1e30f;
            }
        }
        float p0[4], p1[4];
        #pragma unroll
        for (int r = 0; r < 4; r++) { p0[r] = exp2f(s0[r] * qsc); lsum += p0[r]; }
        #pragma unroll
        for (int r = 0; r < 4; r++) { p1[r] = exp2f(s1[r] * qsc); lsum += p1[r]; }

        unsigned short* pb = &Pt[w][0];
        *(uint2*)&pb[q_ * 40 + quad * 4] =
            make_uint2(pk2bf(p0[0], p0[1]), pk2bf(p0[2], p0[3]));
        *(uint2*)&pb[q_ * 40 + 16 + quad * 4] =
            make_uint2(pk2bf(p1[0], p1[1]), pk2bf(p1[2], p1[3]));
        bf16x8 pf = *(const bf16x8*)&pb[q_ * 40 + quad * 8];

        #pragma unroll
        for (int c = 0; c < 4; c++) {
            bf16x8 vf = *(const bf16x8*)&vs[(c * 16 + q_) * 40 + quad * 8];
            accO[c] = __builtin_amdgcn_mfma_f32_16x16x32_bf16(vf, pf, accO[c], 0, 0, 0);
        }

        if (kt + 1 < ntiles) {
            *(uint4*)&KS[nxt][krow * 72 + kseg * 8] = krn;
            *(uint4*)&VS[nxt][vrow * 40 + vseg * 8] = vrn;
        }
        __syncthreads();
    }

    lsum += __shfl_xor(lsum, 16);
    lsum += __shfl_xor(lsum, 32);
    float invl = 1.0f / lsum;
    unsigned short* yp = g_y + ((size_t)(b * Tn + qg) * NHn + h) * 64;
    #pragma unroll
    for (int c = 0; c < 4; c++) {
        uint2 o = make_uint2(pk2bf(accO[c][0] * invl, accO[c][1] * invl),
                             pk2bf(accO[c][2] * invl, accO[c][3] * invl));
        *(uint2*)&yp[c * 16 + quad * 4] = o;
    }
}

// ----------------------------------------------------------------------------
extern "C" void kernel_launch(void* const* d_in, const int* in_sizes, int n_in,
                              void* d_out, int out_size, void* d_ws, size_t ws_size,
                              hipStream_t stream) {
    const float* x  = (const float*)d_in[0];
    const float* Wq = (const float*)d_in[1];
    const float* Wk = (const float*)d_in[2];
    const float* Wv = (const float*)d_in[3];
    const float* Wp = (const float*)d_in[4];
    const float* qg = (const float*)d_in[5];
    const float* Aq = (const float*)d_in[6];
    const float* Bq = (const float*)d_in[7];
    const float* Av = (const float*)d_in[8];
    const float* Bv = (const float*)d_in[9];
    float* out = (float*)d_out;

    lora_tmp<<<dim3(Rn / 4), dim3(256), 0, stream>>>(x, Aq, Av);
    cast_w<<<dim3((NQ4 * 2 + NK4 * 2) / 256), dim3(256), 0, stream>>>(Wq, Wk, Wv, Wp);

    gemm_bt<1, 0, 0, 0><<<dim3(Dn / 64, Rn / 128), dim3(256), 0, stream>>>(
        nullptr, Bq, Rn, Dn, Dn);
    gemm_bt<0, 1, 0, 0><<<dim3(KDn / 64, Rn / 128), dim3(256), 0, stream>>>(
        nullptr, nullptr, Rn, KDn, Dn);
    gemm_bt<1, 2, 0, 1><<<dim3(KDn / 64, Rn / 128), dim3(256), 0, stream>>>(
        nullptr, Bv, Rn, KDn, Dn);
    nrg_kernel<<<dim3(Rn, 5), dim3(256), 0, stream>>>(qg);
    attn_kernel<<<dim3(Tn / 16, NKVn, 2), dim3(256), 0, stream>>>();
    gemm_bt<0, 3, 1, 0><<<dim3(Dn / 64, Rn / 128), dim3(256), 0, stream>>>(
        out, nullptr, Rn, Dn, Dn);
}

// Round 11
// 256.615 us; speedup vs baseline: 1.2227x; 1.1630x over previous
//
#include <hip/hip_runtime.h>

#define Tn   2048
#define Dn   1024
#define KDn  256
#define NHn  16
#define NKVn 4
#define Rn   4096   // B*T

typedef short bf16x8 __attribute__((ext_vector_type(8)));
typedef float f32x4  __attribute__((ext_vector_type(4)));
typedef const __attribute__((address_space(1))) unsigned* gas_p;
typedef __attribute__((address_space(3))) unsigned* las_p;

// ---- device-global intermediates; referenced ONLY from device code ---------
__device__ unsigned short g_q[(size_t)Rn * Dn];              // [b][t][h][d]
__device__ unsigned short g_k[(size_t)Rn * KDn];             // [b][t][kvh][d]
__device__ unsigned short g_vt[(size_t)2 * NKVn * 64 * Tn];  // [b][kvh][d][t]
__device__ unsigned short g_y[(size_t)Rn * Dn];              // [b][t][h][d]
__device__ unsigned short g_xb[(size_t)Rn * Dn];             // bf16 x
__device__ unsigned short g_wq[(size_t)Dn * Dn];
__device__ unsigned short g_wk[(size_t)KDn * Dn];
__device__ unsigned short g_wv[(size_t)KDn * Dn];
__device__ unsigned short g_wp[(size_t)Dn * Dn];
__device__ float g_tq[Rn * 8];
__device__ float g_tv[Rn * 8];

static __device__ __forceinline__ float bf2f(unsigned short u) {
    return __uint_as_float(((unsigned)u) << 16);
}
static __device__ __forceinline__ unsigned short f2bf(float f) {
    unsigned u = __float_as_uint(f);
    u += 0x7fffu + ((u >> 16) & 1u);   // round-to-nearest-even
    return (unsigned short)(u >> 16);
}
static __device__ __forceinline__ unsigned pk2bf(float a, float b) {
    return (unsigned)f2bf(a) | ((unsigned)f2bf(b) << 16);
}
static __device__ __forceinline__ float wave_sum(float s) {
    #pragma unroll
    for (int off = 32; off; off >>= 1) s += __shfl_xor(s, off);
    return s;
}

// ------- LoRA temporaries tq/tv = x@A^T  +  fused x fp32->bf16 cast ---------
__global__ __launch_bounds__(256)
void lora_tmp(const float* __restrict__ x,
              const float* __restrict__ Aq,
              const float* __restrict__ Av) {
    int tid = threadIdx.x, wave = tid >> 6, lane = tid & 63;
    int row = blockIdx.x * 4 + wave;
    const float2* xr = (const float2*)(x + (size_t)row * Dn);
    unsigned* xbo = (unsigned*)g_xb + (size_t)row * (Dn / 2);
    float aq[8], av[8];
    #pragma unroll
    for (int r = 0; r < 8; r++) { aq[r] = 0.f; av[r] = 0.f; }
    for (int it = 0; it < Dn / 128; it++) {
        int j = it * 64 + lane;
        float2 xv = xr[j];
        xbo[j] = pk2bf(xv.x, xv.y);
        #pragma unroll
        for (int r = 0; r < 8; r++) {
            float2 a2 = ((const float2*)(Aq + (size_t)r * Dn))[j];
            aq[r] += xv.x * a2.x + xv.y * a2.y;
        }
        #pragma unroll
        for (int r = 0; r < 8; r++) {
            float2 a2 = ((const float2*)(Av + (size_t)r * Dn))[j];
            av[r] += xv.x * a2.x + xv.y * a2.y;
        }
    }
    #pragma unroll
    for (int r = 0; r < 8; r++) { aq[r] = wave_sum(aq[r]); av[r] = wave_sum(av[r]); }
    if (lane == 0) {
        #pragma unroll
        for (int r = 0; r < 8; r++) { g_tq[row * 8 + r] = aq[r]; g_tv[row * 8 + r] = av[r]; }
    }
}

// ---------------- single fused weight cast (Wq|Wk|Wv|Wp -> bf16) ------------
#define NQ4 (Dn * Dn / 4)
#define NK4 (KDn * Dn / 4)
__global__ __launch_bounds__(256)
void cast_w(const float* __restrict__ Wq, const float* __restrict__ Wk,
            const float* __restrict__ Wv, const float* __restrict__ Wp) {
    int i = blockIdx.x * 256 + threadIdx.x;
    const float* src; unsigned short* dst; int o;
    if      (i < NQ4)                 { src = Wq; dst = g_wq; o = i; }
    else if (i < NQ4 + NK4)           { src = Wk; dst = g_wk; o = i - NQ4; }
    else if (i < NQ4 + 2 * NK4)       { src = Wv; dst = g_wv; o = i - NQ4 - NK4; }
    else                              { src = Wp; dst = g_wp; o = i - NQ4 - 2 * NK4; }
    float4 v = ((const float4*)src)[o];
    ((uint2*)dst)[o] = make_uint2(pk2bf(v.x, v.y), pk2bf(v.z, v.w));
}

// ---- MFMA GEMM, 128x64 tile, gll double-buffer -----------------------------
// MODE 0 = fused QKV: A=g_xb, W region per block over concatenated N=1536
//   (cols 0..1023 Wq->g_q+LoRA, 1024..1279 Wk->g_k, 1280..1535 Wv->g_vt+LoRA)
// MODE 1 = out: A=g_y, W=g_wp, C=Cout fp32.
template<int MODE>
__global__ __launch_bounds__(256, 2)
void gemm_bt(float* __restrict__ Cout, const float* __restrict__ BqL,
             const float* __restrict__ BvL, int M, int K) {
    const unsigned short* A = (MODE == 0) ? g_xb : g_y;
    int n0 = blockIdx.x * 64, m0 = blockIdx.y * 128;
    const unsigned short* W;
    int wroff, region;
    if (MODE == 0) {
        if (n0 < 1024)      { W = g_wq; wroff = n0;        region = 0; }
        else if (n0 < 1280) { W = g_wk; wroff = n0 - 1024; region = 1; }
        else                { W = g_wv; wroff = n0 - 1280; region = 2; }
    } else { W = g_wp; wroff = n0; region = 3; }

    __shared__ __align__(16) unsigned short As[2][128 * 32];  // 64B rows
    __shared__ __align__(16) unsigned short Ws[2][64 * 32];
    int tid = threadIdx.x;
    int w = tid >> 6, lane = tid & 63;
    int m_ = lane & 15, quad = lane >> 4;

    int lrow = lane >> 2, lseg = (lane & 3) * 8;
    const unsigned short* agp0 = A + (size_t)(m0 + w * 32 + lrow) * K + lseg;
    const unsigned short* agp1 = A + (size_t)(m0 + w * 32 + 16 + lrow) * K + lseg;
    const unsigned short* wgp  = W + (size_t)(wroff + w * 16 + lrow) * K + lseg;
    int albase0 = (w * 32) * 32;
    int albase1 = (w * 32 + 16) * 32;
    int wlbase  = (w * 16) * 32;

    f32x4 acc[2][4];
    #pragma unroll
    for (int im = 0; im < 2; im++)
        #pragma unroll
        for (int in = 0; in < 4; in++) acc[im][in] = (f32x4){0.f, 0.f, 0.f, 0.f};

    __builtin_amdgcn_global_load_lds((gas_p)agp0, (las_p)&As[0][albase0], 16, 0, 0);
    __builtin_amdgcn_global_load_lds((gas_p)agp1, (las_p)&As[0][albase1], 16, 0, 0);
    __builtin_amdgcn_global_load_lds((gas_p)wgp,  (las_p)&Ws[0][wlbase],  16, 0, 0);

    int nk = K / 32;
    for (int kt = 0; kt < nk; kt++) {
        __syncthreads();
        int cur = kt & 1, nxt = cur ^ 1;
        if (kt + 1 < nk) {
            int ko = (kt + 1) * 32;
            __builtin_amdgcn_global_load_lds((gas_p)(agp0 + ko), (las_p)&As[nxt][albase0], 16, 0, 0);
            __builtin_amdgcn_global_load_lds((gas_p)(agp1 + ko), (las_p)&As[nxt][albase1], 16, 0, 0);
            __builtin_amdgcn_global_load_lds((gas_p)(wgp  + ko), (las_p)&Ws[nxt][wlbase],  16, 0, 0);
        }
        bf16x8 bf[4];
        #pragma unroll
        for (int in = 0; in < 4; in++)
            bf[in] = *(const bf16x8*)&Ws[cur][(in * 16 + m_) * 32 + quad * 8];
        #pragma unroll
        for (int im = 0; im < 2; im++) {
            bf16x8 af = *(const bf16x8*)&As[cur][(w * 32 + im * 16 + m_) * 32 + quad * 8];
            #pragma unroll
            for (int in = 0; in < 4; in++)
                acc[im][in] = __builtin_amdgcn_mfma_f32_16x16x32_bf16(af, bf[in], acc[im][in], 0, 0, 0);
        }
    }

    // epilogue
    float blc[4][8];
    if (MODE == 0 && region != 1) {
        #pragma unroll
        for (int in = 0; in < 4; in++) {
            const float* bp = (region == 0) ? BqL + (size_t)(n0 + in * 16 + m_) * 8
                                            : BvL + (size_t)(n0 - 1280 + in * 16 + m_) * 8;
            #pragma unroll
            for (int j = 0; j < 8; j++) blc[in][j] = bp[j];
        }
    }
    const float* tl = (region == 0) ? g_tq : g_tv;
    #pragma unroll
    for (int im = 0; im < 2; im++) {
        #pragma unroll
        for (int r = 0; r < 4; r++) {
            int row = m0 + w * 32 + im * 16 + quad * 4 + r;
            float tv8[8];
            if (MODE == 0 && region != 1) {
                const float* tp = tl + (size_t)row * 8;
                #pragma unroll
                for (int j = 0; j < 8; j++) tv8[j] = tp[j];
            }
            #pragma unroll
            for (int in = 0; in < 4; in++) {
                int col = n0 + in * 16 + m_;
                float val = acc[im][in][r];
                if (MODE == 0 && region != 1) {
                    #pragma unroll
                    for (int j = 0; j < 8; j++) val += tv8[j] * blc[in][j];
                }
                if (MODE == 1) {
                    Cout[(size_t)row * Dn + col] = val;
                } else if (region == 0) {
                    g_q[(size_t)row * Dn + col] = f2bf(val);
                } else if (region == 1) {
                    g_k[(size_t)row * KDn + (col - 1024)] = f2bf(val);
                } else {
                    int cv = col - 1280;
                    int b = row >> 11, t = row & (Tn - 1);
                    g_vt[(((size_t)(b * NKVn + (cv >> 6)) * 64) + (cv & 63)) * Tn + t] = f2bf(val);
                }
            }
        }
    }
}

// -------- RMSNorm + partial RoPE (+gain for q), in place on g_q / g_k -------
__global__ __launch_bounds__(256)
void nrg_kernel(const float* __restrict__ gain) {
    int tid = threadIdx.x;
    int u = blockIdx.y * 4 + (tid >> 6);   // 0..15: q heads, 16..19: k heads
    int lane = tid & 63;
    int row = blockIdx.x;
    int t = row & (Tn - 1);

    unsigned short* buf;
    size_t off;
    if (u < 16) { buf = g_q; off = (size_t)row * Dn + u * 64 + lane; }
    else        { buf = g_k; off = (size_t)row * KDn + (u - 16) * 64 + lane; }

    float v = bf2f(buf[off]);
    float s = wave_sum(v * v);
    float xv = v * rsqrtf(s * (1.0f / 64.0f) + 1.1920929e-7f);
    float p = __shfl_xor(xv, 8);
    if (lane < 16) {
        int j = lane & 7;
        float fr = (float)t * exp2f(-(float)j * 1.6609640474436813f); // base^(-j/8)
        float c = cosf(fr), sn = sinf(fr);
        xv = (lane < 8) ? (xv * c + p * sn) : (p * sn - xv * c);
    }
    if (u < 16) xv *= gain[u];
    buf[off] = f2bf(xv);
}

// -------- MFMA flash attention, 64-key tiles (half the barriers of r8) ------
// Block = 4 heads sharing one kv group; K/V staged to LDS double-buffered.
// Static softmax (|S*qsc| <= 60.6 < 127). Per tile: 8 S-MFMA + 8 PV-MFMA.
__global__ __launch_bounds__(256, 3)
void attn_kernel() {
    __shared__ __align__(16) unsigned short KS[2][64 * 72];  // row=key, 144B
    __shared__ __align__(16) unsigned short VS[2][64 * 72];  // row=d, 64 keys
    __shared__ __align__(16) unsigned short Pt[4][16 * 72];  // per-wave P^T
    const float qsc = 0.125f * 1.44269504088896f;  // 1/sqrt(64) * log2(e)
    int tid = threadIdx.x;
    int w = tid >> 6, lane = tid & 63;
    int q_ = lane & 15, quad = lane >> 4;
    int b = blockIdx.z, kvh = blockIdx.y, h = kvh * 4 + w;
    int qb = blockIdx.x * 16;
    int qg = qb + q_;

    const unsigned short* qrow =
        g_q + ((size_t)(b * Tn + qg) * NHn + h) * 64 + quad * 8;
    bf16x8 Qf0 = *(const bf16x8*)qrow;
    bf16x8 Qf1 = *(const bf16x8*)(qrow + 32);

    // staging: 256 thr x 2 x 16B per matrix per tile (64 rows x 128B)
    int srow = tid >> 2, sseg = (tid & 3) * 16;
    const unsigned short* kgp =
        g_k + ((size_t)(b * Tn + srow) * NKVn + kvh) * 64 + sseg;
    const unsigned short* vgp =
        g_vt + ((size_t)(b * NKVn + kvh) * 64 + srow) * Tn + sseg;

    f32x4 accO[4];
    #pragma unroll
    for (int i = 0; i < 4; i++) accO[i] = (f32x4){0.f, 0.f, 0.f, 0.f};
    float lsum = 0.f;
    int ntiles = (qb + 79) >> 6;   // ceil((qb+16)/64); block-uniform

    {
        uint4 ka = *(const uint4*)kgp, kb = *(const uint4*)(kgp + 8);
        uint4 va = *(const uint4*)vgp, vb = *(const uint4*)(vgp + 8);
        *(uint4*)&KS[0][srow * 72 + sseg] = ka;
        *(uint4*)&KS[0][srow * 72 + sseg + 8] = kb;
        *(uint4*)&VS[0][srow * 72 + sseg] = va;
        *(uint4*)&VS[0][srow * 72 + sseg + 8] = vb;
    }
    __syncthreads();

    for (int kt = 0; kt < ntiles; kt++) {
        int cur = kt & 1, nxt = cur ^ 1;
        uint4 kan = make_uint4(0,0,0,0), kbn = kan, van = kan, vbn = kan;
        if (kt + 1 < ntiles) {
            const unsigned short* kp = kgp + (size_t)(kt + 1) * (64 * NKVn * 64);
            const unsigned short* vp = vgp + (kt + 1) * 64;
            kan = *(const uint4*)kp; kbn = *(const uint4*)(kp + 8);
            van = *(const uint4*)vp; vbn = *(const uint4*)(vp + 8);
        }

        const unsigned short* ks = &KS[cur][0];
        const unsigned short* vs = &VS[cur][0];
        f32x4 s[4];
        #pragma unroll
        for (int ss = 0; ss < 4; ss++) {
            bf16x8 ka = *(const bf16x8*)&ks[(ss * 16 + q_) * 72 + quad * 8];
            bf16x8 kb = *(const bf16x8*)&ks[(ss * 16 + q_) * 72 + 32 + quad * 8];
            s[ss] = (f32x4){0.f, 0.f, 0.f, 0.f};
            s[ss] = __builtin_amdgcn_mfma_f32_16x16x32_bf16(ka, Qf0, s[ss], 0, 0, 0);
            s[ss] = __builtin_amdgcn_mfma_f32_16x16x32_bf16(kb, Qf1, s[ss], 0, 0, 0);
        }

        if (kt == ntiles - 1) {   // only the last tile can cross the diagonal
            #pragma unroll
            for (int ss = 0; ss < 4; ss++) {
                int k0 = kt * 64 + ss * 16 + quad * 4;
                #pragma unroll
                for (int r = 0; r < 4; r++)
                    if (k0 + r > qg) s[ss][r] = -1e30f;
            }
        }
        float p[4][4];
        #pragma unroll
        for (int ss = 0; ss < 4; ss++)
            #pragma unroll
            for (int r = 0; r < 4; r++) {
                p[ss][r] = exp2f(s[ss][r] * qsc);
                lsum += p[ss][r];
            }

        unsigned short* pb = &Pt[w][0];
        #pragma unroll
        for (int ss = 0; ss < 4; ss++)
            *(uint2*)&pb[q_ * 72 + ss * 16 + quad * 4] =
                make_uint2(pk2bf(p[ss][0], p[ss][1]), pk2bf(p[ss][2], p[ss][3]));
        bf16x8 pf0 = *(const bf16x8*)&pb[q_ * 72 + quad * 8];
        bf16x8 pf1 = *(const bf16x8*)&pb[q_ * 72 + 32 + quad * 8];

        #pragma unroll
        for (int c = 0; c < 4; c++) {
            bf16x8 vf0 = *(const bf16x8*)&vs[(c * 16 + q_) * 72 + quad * 8];
            bf16x8 vf1 = *(const bf16x8*)&vs[(c * 16 + q_) * 72 + 32 + quad * 8];
            accO[c] = __builtin_amdgcn_mfma_f32_16x16x32_bf16(vf0, pf0, accO[c], 0, 0, 0);
            accO[c] = __builtin_amdgcn_mfma_f32_16x16x32_bf16(vf1, pf1, accO[c], 0, 0, 0);
        }

        if (kt + 1 < ntiles) {
            *(uint4*)&KS[nxt][srow * 72 + sseg] = kan;
            *(uint4*)&KS[nxt][srow * 72 + sseg + 8] = kbn;
            *(uint4*)&VS[nxt][srow * 72 + sseg] = van;
            *(uint4*)&VS[nxt][srow * 72 + sseg + 8] = vbn;
        }
        __syncthreads();
    }

    lsum += __shfl_xor(lsum, 16);
    lsum += __shfl_xor(lsum, 32);
    float invl = 1.0f / lsum;
    unsigned short* yp = g_y + ((size_t)(b * Tn + qg) * NHn + h) * 64;
    #pragma unroll
    for (int c = 0; c < 4; c++) {
        uint2 o = make_uint2(pk2bf(accO[c][0] * invl, accO[c][1] * invl),
                             pk2bf(accO[c][2] * invl, accO[c][3] * invl));
        *(uint2*)&yp[c * 16 + quad * 4] = o;
    }
}

// ----------------------------------------------------------------------------
extern "C" void kernel_launch(void* const* d_in, const int* in_sizes, int n_in,
                              void* d_out, int out_size, void* d_ws, size_t ws_size,
                              hipStream_t stream) {
    const float* x  = (const float*)d_in[0];
    const float* Wq = (const float*)d_in[1];
    const float* Wk = (const float*)d_in[2];
    const float* Wv = (const float*)d_in[3];
    const float* Wp = (const float*)d_in[4];
    const float* qg = (const float*)d_in[5];
    const float* Aq = (const float*)d_in[6];
    const float* Bq = (const float*)d_in[7];
    const float* Av = (const float*)d_in[8];
    const float* Bv = (const float*)d_in[9];
    float* out = (float*)d_out;

    lora_tmp<<<dim3(Rn / 4), dim3(256), 0, stream>>>(x, Aq, Av);
    cast_w<<<dim3((NQ4 * 2 + NK4 * 2) / 256), dim3(256), 0, stream>>>(Wq, Wk, Wv, Wp);
    gemm_bt<0><<<dim3(1536 / 64, Rn / 128), dim3(256), 0, stream>>>(
        nullptr, Bq, Bv, Rn, Dn);
    nrg_kernel<<<dim3(Rn, 5), dim3(256), 0, stream>>>(qg);
    attn_kernel<<<dim3(Tn / 16, NKVn, 2), dim3(256), 0, stream>>>();
    gemm_bt<1><<<dim3(Dn / 64, Rn / 128), dim3(256), 0, stream>>>(
        out, nullptr, nullptr, Rn, Dn);
}

// Round 12
// 236.207 us; speedup vs baseline: 1.3283x; 1.0864x over previous
//
#include <hip/hip_runtime.h>

#define Tn   2048
#define Dn   1024
#define KDn  256
#define NHn  16
#define NKVn 4
#define Rn   4096   // B*T

typedef short bf16x8 __attribute__((ext_vector_type(8)));
typedef float f32x4  __attribute__((ext_vector_type(4)));
typedef const __attribute__((address_space(1))) unsigned* gas_p;
typedef __attribute__((address_space(3))) unsigned* las_p;

// ---- device-global intermediates; referenced ONLY from device code ---------
__device__ unsigned short g_q[(size_t)Rn * Dn];              // [b][t][h][d]
__device__ unsigned short g_k[(size_t)Rn * KDn];             // [b][t][kvh][d]
__device__ unsigned short g_vt[(size_t)2 * NKVn * 64 * Tn];  // [b][kvh][d][t]
__device__ unsigned short g_y[(size_t)Rn * Dn];              // [b][t][h][d]
__device__ unsigned short g_xb[(size_t)Rn * Dn];             // bf16 x
__device__ unsigned short g_wq[(size_t)Dn * Dn];
__device__ unsigned short g_wk[(size_t)KDn * Dn];
__device__ unsigned short g_wv[(size_t)KDn * Dn];
__device__ unsigned short g_wp[(size_t)Dn * Dn];
__device__ float g_tq[Rn * 8];
__device__ float g_tv[Rn * 8];

static __device__ __forceinline__ float bf2f(unsigned short u) {
    return __uint_as_float(((unsigned)u) << 16);
}
static __device__ __forceinline__ unsigned short f2bf(float f) {
    unsigned u = __float_as_uint(f);
    u += 0x7fffu + ((u >> 16) & 1u);   // round-to-nearest-even
    return (unsigned short)(u >> 16);
}
static __device__ __forceinline__ unsigned pk2bf(float a, float b) {
    return (unsigned)f2bf(a) | ((unsigned)f2bf(b) << 16);
}
static __device__ __forceinline__ float wave_sum(float s) {
    #pragma unroll
    for (int off = 32; off; off >>= 1) s += __shfl_xor(s, off);
    return s;
}

// ------- LoRA temporaries tq/tv = x@A^T  +  fused x fp32->bf16 cast ---------
__global__ __launch_bounds__(256)
void lora_tmp(const float* __restrict__ x,
              const float* __restrict__ Aq,
              const float* __restrict__ Av) {
    int tid = threadIdx.x, wave = tid >> 6, lane = tid & 63;
    int row = blockIdx.x * 4 + wave;
    const float2* xr = (const float2*)(x + (size_t)row * Dn);
    unsigned* xbo = (unsigned*)g_xb + (size_t)row * (Dn / 2);
    float aq[8], av[8];
    #pragma unroll
    for (int r = 0; r < 8; r++) { aq[r] = 0.f; av[r] = 0.f; }
    for (int it = 0; it < Dn / 128; it++) {
        int j = it * 64 + lane;
        float2 xv = xr[j];
        xbo[j] = pk2bf(xv.x, xv.y);
        #pragma unroll
        for (int r = 0; r < 8; r++) {
            float2 a2 = ((const float2*)(Aq + (size_t)r * Dn))[j];
            aq[r] += xv.x * a2.x + xv.y * a2.y;
        }
        #pragma unroll
        for (int r = 0; r < 8; r++) {
            float2 a2 = ((const float2*)(Av + (size_t)r * Dn))[j];
            av[r] += xv.x * a2.x + xv.y * a2.y;
        }
    }
    #pragma unroll
    for (int r = 0; r < 8; r++) { aq[r] = wave_sum(aq[r]); av[r] = wave_sum(av[r]); }
    if (lane == 0) {
        #pragma unroll
        for (int r = 0; r < 8; r++) { g_tq[row * 8 + r] = aq[r]; g_tv[row * 8 + r] = av[r]; }
    }
}

// ---------------- single fused weight cast (Wq|Wk|Wv|Wp -> bf16) ------------
#define NQ4 (Dn * Dn / 4)
#define NK4 (KDn * Dn / 4)
__global__ __launch_bounds__(256)
void cast_w(const float* __restrict__ Wq, const float* __restrict__ Wk,
            const float* __restrict__ Wv, const float* __restrict__ Wp) {
    int i = blockIdx.x * 256 + threadIdx.x;
    const float* src; unsigned short* dst; int o;
    if      (i < NQ4)                 { src = Wq; dst = g_wq; o = i; }
    else if (i < NQ4 + NK4)           { src = Wk; dst = g_wk; o = i - NQ4; }
    else if (i < NQ4 + 2 * NK4)       { src = Wv; dst = g_wv; o = i - NQ4 - NK4; }
    else                              { src = Wp; dst = g_wp; o = i - NQ4 - 2 * NK4; }
    float4 v = ((const float4*)src)[o];
    ((uint2*)dst)[o] = make_uint2(pk2bf(v.x, v.y), pk2bf(v.z, v.w));
}

// ---- MFMA GEMM, 128x64 tile, gll double-buffer -----------------------------
// MODE 0 = fused QKV over concatenated N=1536:
//   region 0 (cols 0..1023):    Wq -> +LoRA -> RMSNorm+RoPE+gain -> g_q
//   region 1 (cols 1024..1279): Wk ->          RMSNorm+RoPE       -> g_k
//   region 2 (cols 1280..1535): Wv -> +LoRA -> LDS transpose -> g_vt coalesced
// MODE 1 = out: A=g_y, W=g_wp, C=Cout fp32.
template<int MODE>
__global__ __launch_bounds__(256, 2)
void gemm_bt(float* __restrict__ Cout, const float* __restrict__ BqL,
             const float* __restrict__ BvL, const float* __restrict__ qgain,
             int M, int K) {
    const unsigned short* A = (MODE == 0) ? g_xb : g_y;
    int n0 = blockIdx.x * 64, m0 = blockIdx.y * 128;
    const unsigned short* W;
    int wroff, region;
    if (MODE == 0) {
        if (n0 < 1024)      { W = g_wq; wroff = n0;        region = 0; }
        else if (n0 < 1280) { W = g_wk; wroff = n0 - 1024; region = 1; }
        else                { W = g_wv; wroff = n0 - 1280; region = 2; }
    } else { W = g_wp; wroff = n0; region = 3; }

    // SM: [0..8191] = As double buffer (2 x 128 x 32 shorts, 64B rows)
    //     [8192..12287] = Ws double buffer (2 x 64 x 32 shorts)
    //     region-2 epilogue reuses SM[0..8703] as 64 x (stride 136) transpose buf
    __shared__ __align__(16) unsigned short SM[12288];
    int tid = threadIdx.x;
    int w = tid >> 6, lane = tid & 63;
    int m_ = lane & 15, quad = lane >> 4;

    int lrow = lane >> 2, lseg = (lane & 3) * 8;
    const unsigned short* agp0 = A + (size_t)(m0 + w * 32 + lrow) * K + lseg;
    const unsigned short* agp1 = A + (size_t)(m0 + w * 32 + 16 + lrow) * K + lseg;
    const unsigned short* wgp  = W + (size_t)(wroff + w * 16 + lrow) * K + lseg;
    int albase0 = (w * 32) * 32;
    int albase1 = (w * 32 + 16) * 32;
    int wlbase  = 8192 + (w * 16) * 32;

    f32x4 acc[2][4];
    #pragma unroll
    for (int im = 0; im < 2; im++)
        #pragma unroll
        for (int in = 0; in < 4; in++) acc[im][in] = (f32x4){0.f, 0.f, 0.f, 0.f};

    __builtin_amdgcn_global_load_lds((gas_p)agp0, (las_p)&SM[albase0], 16, 0, 0);
    __builtin_amdgcn_global_load_lds((gas_p)agp1, (las_p)&SM[albase1], 16, 0, 0);
    __builtin_amdgcn_global_load_lds((gas_p)wgp,  (las_p)&SM[wlbase],  16, 0, 0);

    int nk = K / 32;
    for (int kt = 0; kt < nk; kt++) {
        __syncthreads();
        int cur = kt & 1, nxt = cur ^ 1;
        if (kt + 1 < nk) {
            int ko = (kt + 1) * 32;
            __builtin_amdgcn_global_load_lds((gas_p)(agp0 + ko), (las_p)&SM[nxt * 4096 + albase0], 16, 0, 0);
            __builtin_amdgcn_global_load_lds((gas_p)(agp1 + ko), (las_p)&SM[nxt * 4096 + albase1], 16, 0, 0);
            __builtin_amdgcn_global_load_lds((gas_p)(wgp  + ko), (las_p)&SM[wlbase + nxt * 2048], 16, 0, 0);
        }
        bf16x8 bf[4];
        #pragma unroll
        for (int in = 0; in < 4; in++)
            bf[in] = *(const bf16x8*)&SM[8192 + cur * 2048 + (in * 16 + m_) * 32 + quad * 8];
        #pragma unroll
        for (int im = 0; im < 2; im++) {
            bf16x8 af = *(const bf16x8*)&SM[cur * 4096 + (w * 32 + im * 16 + m_) * 32 + quad * 8];
            #pragma unroll
            for (int in = 0; in < 4; in++)
                acc[im][in] = __builtin_amdgcn_mfma_f32_16x16x32_bf16(af, bf[in], acc[im][in], 0, 0, 0);
        }
    }

    if (MODE == 1) {
        #pragma unroll
        for (int im = 0; im < 2; im++)
            #pragma unroll
            for (int r = 0; r < 4; r++) {
                int row = m0 + w * 32 + im * 16 + quad * 4 + r;
                #pragma unroll
                for (int in = 0; in < 4; in++)
                    Cout[(size_t)row * Dn + (n0 + in * 16 + m_)] = acc[im][in][r];
            }
        return;
    }

    if (region <= 1) {
        // ---- fused LoRA(q) + RMSNorm + partial RoPE + gain(q) ----
        float blc[4][8];
        if (region == 0) {
            #pragma unroll
            for (int in = 0; in < 4; in++) {
                const float* bp = BqL + (size_t)(n0 + in * 16 + m_) * 8;
                #pragma unroll
                for (int j = 0; j < 8; j++) blc[in][j] = bp[j];
            }
        }
        float ghead = (region == 0) ? qgain[n0 >> 6] : 1.0f;
        #pragma unroll
        for (int im = 0; im < 2; im++) {
            #pragma unroll
            for (int r = 0; r < 4; r++) {
                int row = m0 + w * 32 + im * 16 + quad * 4 + r;
                float vv[4];
                float ss = 0.f;
                if (region == 0) {
                    const float* tp = g_tq + (size_t)row * 8;
                    float tv8[8];
                    #pragma unroll
                    for (int j = 0; j < 8; j++) tv8[j] = tp[j];
                    #pragma unroll
                    for (int in = 0; in < 4; in++) {
                        float val = acc[im][in][r];
                        #pragma unroll
                        for (int j = 0; j < 8; j++) val += tv8[j] * blc[in][j];
                        vv[in] = val; ss += val * val;
                    }
                } else {
                    #pragma unroll
                    for (int in = 0; in < 4; in++) { vv[in] = acc[im][in][r]; ss += vv[in] * vv[in]; }
                }
                ss += __shfl_xor(ss, 1); ss += __shfl_xor(ss, 2);
                ss += __shfl_xor(ss, 4); ss += __shfl_xor(ss, 8);
                float rs = rsqrtf(ss * (1.0f / 64.0f) + 1.1920929e-7f);
                #pragma unroll
                for (int in = 0; in < 4; in++) vv[in] *= rs;
                float p = __shfl_xor(vv[0], 8);
                int t = row & (Tn - 1);
                float fr = (float)t * exp2f(-(float)(m_ & 7) * 1.6609640474436813f);
                float c = cosf(fr), sn = sinf(fr);
                if (m_ < 16) vv[0] = (m_ < 8) ? vv[0] * c + p * sn : p * sn - vv[0] * c;
                #pragma unroll
                for (int in = 0; in < 4; in++) {
                    float val = vv[in] * ghead;
                    int col = n0 + in * 16 + m_;
                    if (region == 0) g_q[(size_t)row * Dn + col] = f2bf(val);
                    else             g_k[(size_t)row * KDn + (col - 1024)] = f2bf(val);
                }
            }
        }
    } else {
        // ---- region 2: LoRA(v) + LDS transpose -> coalesced g_vt store ----
        float blc[4][8];
        #pragma unroll
        for (int in = 0; in < 4; in++) {
            const float* bp = BvL + (size_t)(n0 - 1280 + in * 16 + m_) * 8;
            #pragma unroll
            for (int j = 0; j < 8; j++) blc[in][j] = bp[j];
        }
        __syncthreads();   // k-loop LDS now dead for all waves
        #pragma unroll
        for (int im = 0; im < 2; im++) {
            #pragma unroll
            for (int r = 0; r < 4; r++) {
                int rl = w * 32 + im * 16 + quad * 4 + r;   // local t
                const float* tp = g_tv + (size_t)(m0 + rl) * 8;
                float tv8[8];
                #pragma unroll
                for (int j = 0; j < 8; j++) tv8[j] = tp[j];
                #pragma unroll
                for (int in = 0; in < 4; in++) {
                    float val = acc[im][in][r];
                    #pragma unroll
                    for (int j = 0; j < 8; j++) val += tv8[j] * blc[in][j];
                    SM[(in * 16 + m_) * 136 + rl] = f2bf(val);  // [d][t], stride 136
                }
            }
        }
        __syncthreads();
        int d = tid >> 2, tseg = (tid & 3) * 32;
        int bb = m0 >> 11, t0 = m0 & (Tn - 1);
        int kvh = (n0 - 1280) >> 6;
        unsigned short* dst = g_vt + (((size_t)(bb * NKVn + kvh) * 64) + d) * Tn + t0 + tseg;
        const uint4* srcv = (const uint4*)&SM[d * 136 + tseg];
        uint4 c0 = srcv[0], c1 = srcv[1], c2 = srcv[2], c3 = srcv[3];
        ((uint4*)dst)[0] = c0; ((uint4*)dst)[1] = c1;
        ((uint4*)dst)[2] = c2; ((uint4*)dst)[3] = c3;
    }
}

// -------- MFMA flash attention, 64-key tiles (r11-exact) --------------------
__global__ __launch_bounds__(256, 3)
void attn_kernel() {
    __shared__ __align__(16) unsigned short KS[2][64 * 72];
    __shared__ __align__(16) unsigned short VS[2][64 * 72];
    __shared__ __align__(16) unsigned short Pt[4][16 * 72];
    const float qsc = 0.125f * 1.44269504088896f;  // 1/sqrt(64) * log2(e)
    int tid = threadIdx.x;
    int w = tid >> 6, lane = tid & 63;
    int q_ = lane & 15, quad = lane >> 4;
    int b = blockIdx.z, kvh = blockIdx.y, h = kvh * 4 + w;
    int qb = blockIdx.x * 16;
    int qg = qb + q_;

    const unsigned short* qrow =
        g_q + ((size_t)(b * Tn + qg) * NHn + h) * 64 + quad * 8;
    bf16x8 Qf0 = *(const bf16x8*)qrow;
    bf16x8 Qf1 = *(const bf16x8*)(qrow + 32);

    int srow = tid >> 2, sseg = (tid & 3) * 16;
    const unsigned short* kgp =
        g_k + ((size_t)(b * Tn + srow) * NKVn + kvh) * 64 + sseg;
    const unsigned short* vgp =
        g_vt + ((size_t)(b * NKVn + kvh) * 64 + srow) * Tn + sseg;

    f32x4 accO[4];
    #pragma unroll
    for (int i = 0; i < 4; i++) accO[i] = (f32x4){0.f, 0.f, 0.f, 0.f};
    float lsum = 0.f;
    int ntiles = (qb + 79) >> 6;

    {
        uint4 ka = *(const uint4*)kgp, kb = *(const uint4*)(kgp + 8);
        uint4 va = *(const uint4*)vgp, vb = *(const uint4*)(vgp + 8);
        *(uint4*)&KS[0][srow * 72 + sseg] = ka;
        *(uint4*)&KS[0][srow * 72 + sseg + 8] = kb;
        *(uint4*)&VS[0][srow * 72 + sseg] = va;
        *(uint4*)&VS[0][srow * 72 + sseg + 8] = vb;
    }
    __syncthreads();

    for (int kt = 0; kt < ntiles; kt++) {
        int cur = kt & 1, nxt = cur ^ 1;
        uint4 kan = make_uint4(0,0,0,0), kbn = kan, van = kan, vbn = kan;
        if (kt + 1 < ntiles) {
            const unsigned short* kp = kgp + (size_t)(kt + 1) * (64 * NKVn * 64);
            const unsigned short* vp = vgp + (kt + 1) * 64;
            kan = *(const uint4*)kp; kbn = *(const uint4*)(kp + 8);
            van = *(const uint4*)vp; vbn = *(const uint4*)(vp + 8);
        }

        const unsigned short* ks = &KS[cur][0];
        const unsigned short* vs = &VS[cur][0];
        f32x4 s[4];
        #pragma unroll
        for (int ss = 0; ss < 4; ss++) {
            bf16x8 ka = *(const bf16x8*)&ks[(ss * 16 + q_) * 72 + quad * 8];
            bf16x8 kb = *(const bf16x8*)&ks[(ss * 16 + q_) * 72 + 32 + quad * 8];
            s[ss] = (f32x4){0.f, 0.f, 0.f, 0.f};
            s[ss] = __builtin_amdgcn_mfma_f32_16x16x32_bf16(ka, Qf0, s[ss], 0, 0, 0);
            s[ss] = __builtin_amdgcn_mfma_f32_16x16x32_bf16(kb, Qf1, s[ss], 0, 0, 0);
        }

        if (kt == ntiles - 1) {
            #pragma unroll
            for (int ss = 0; ss < 4; ss++) {
                int k0 = kt * 64 + ss * 16 + quad * 4;
                #pragma unroll
                for (int r = 0; r < 4; r++)
                    if (k0 + r > qg) s[ss][r] = -1e30f;
            }
        }
        float p[4][4];
        #pragma unroll
        for (int ss = 0; ss < 4; ss++)
            #pragma unroll
            for (int r = 0; r < 4; r++) {
                p[ss][r] = exp2f(s[ss][r] * qsc);
                lsum += p[ss][r];
            }

        unsigned short* pb = &Pt[w][0];
        #pragma unroll
        for (int ss = 0; ss < 4; ss++)
            *(uint2*)&pb[q_ * 72 + ss * 16 + quad * 4] =
                make_uint2(pk2bf(p[ss][0], p[ss][1]), pk2bf(p[ss][2], p[ss][3]));
        bf16x8 pf0 = *(const bf16x8*)&pb[q_ * 72 + quad * 8];
        bf16x8 pf1 = *(const bf16x8*)&pb[q_ * 72 + 32 + quad * 8];

        #pragma unroll
        for (int c = 0; c < 4; c++) {
            bf16x8 vf0 = *(const bf16x8*)&vs[(c * 16 + q_) * 72 + quad * 8];
            bf16x8 vf1 = *(const bf16x8*)&vs[(c * 16 + q_) * 72 + 32 + quad * 8];
            accO[c] = __builtin_amdgcn_mfma_f32_16x16x32_bf16(vf0, pf0, accO[c], 0, 0, 0);
            accO[c] = __builtin_amdgcn_mfma_f32_16x16x32_bf16(vf1, pf1, accO[c], 0, 0, 0);
        }

        if (kt + 1 < ntiles) {
            *(uint4*)&KS[nxt][srow * 72 + sseg] = kan;
            *(uint4*)&KS[nxt][srow * 72 + sseg + 8] = kbn;
            *(uint4*)&VS[nxt][srow * 72 + sseg] = van;
            *(uint4*)&VS[nxt][srow * 72 + sseg + 8] = vbn;
        }
        __syncthreads();
    }

    lsum += __shfl_xor(lsum, 16);
    lsum += __shfl_xor(lsum, 32);
    float invl = 1.0f / lsum;
    unsigned short* yp = g_y + ((size_t)(b * Tn + qg) * NHn + h) * 64;
    #pragma unroll
    for (int c = 0; c < 4; c++) {
        uint2 o = make_uint2(pk2bf(accO[c][0] * invl, accO[c][1] * invl),
                             pk2bf(accO[c][2] * invl, accO[c][3] * invl));
        *(uint2*)&yp[c * 16 + quad * 4] = o;
    }
}

// ----------------------------------------------------------------------------
extern "C" void kernel_launch(void* const* d_in, const int* in_sizes, int n_in,
                              void* d_out, int out_size, void* d_ws, size_t ws_size,
                              hipStream_t stream) {
    const float* x  = (const float*)d_in[0];
    const float* Wq = (const float*)d_in[1];
    const float* Wk = (const float*)d_in[2];
    const float* Wv = (const float*)d_in[3];
    const float* Wp = (const float*)d_in[4];
    const float* qg = (const float*)d_in[5];
    const float* Aq = (const float*)d_in[6];
    const float* Bq = (const float*)d_in[7];
    const float* Av = (const float*)d_in[8];
    const float* Bv = (const float*)d_in[9];
    float* out = (float*)d_out;

    lora_tmp<<<dim3(Rn / 4), dim3(256), 0, stream>>>(x, Aq, Av);
    cast_w<<<dim3((NQ4 * 2 + NK4 * 2) / 256), dim3(256), 0, stream>>>(Wq, Wk, Wv, Wp);
    gemm_bt<0><<<dim3(1536 / 64, Rn / 128), dim3(256), 0, stream>>>(
        nullptr, Bq, Bv, qg, Rn, Dn);
    attn_kernel<<<dim3(Tn / 16, NKVn, 2), dim3(256), 0, stream>>>();
    gemm_bt<1><<<dim3(Dn / 64, Rn / 128), dim3(256), 0, stream>>>(
        out, nullptr, nullptr, nullptr, Rn, Dn);
}